// Round 9
// baseline (257.070 us; speedup 1.0000x reference)
//
#include <hip/hip_runtime.h>

#define B_  2
#define N_  65536
#define C_  192
#define NH_ 4
#define HD_ 48
#define GS_ 128
#define NG_ 512
#define NTILES_ 256   // per batch, tile = 256 tokens

typedef __attribute__((ext_vector_type(8))) short short8;
typedef __attribute__((ext_vector_type(4))) short short4v;
typedef __attribute__((ext_vector_type(4))) float f32x4;

__device__ __forceinline__ unsigned short f2bf(float f) {
    unsigned u = __float_as_uint(f);
    unsigned r = (u + 0x7FFFu + ((u >> 16) & 1u)) >> 16;
    return (unsigned short)r;
}
// packed RNE f32x2 -> bf16x2 (low short = a, high short = b)
__device__ __forceinline__ unsigned cvt_pk(float a, float b) {
    unsigned r;
    asm("v_cvt_pk_bf16_f32 %0, %1, %2" : "=v"(r) : "v"(a), "v"(b));
    return r;
}
__device__ __forceinline__ float lo16f(unsigned u) { return __uint_as_float(u << 16); }
__device__ __forceinline__ float hi16f(unsigned u) { return __uint_as_float(u & 0xFFFF0000u); }

// 16x16x16 bf16 MFMA (proven on HW in R5 run)
#if defined(__has_builtin)
#if __has_builtin(__builtin_amdgcn_mfma_f32_16x16x16bf16_1k)
#define HAVE_MFMA16_1K 1
#endif
#endif
__device__ __forceinline__ f32x4 mfma16(short4v a, short4v b, f32x4 c) {
#ifdef HAVE_MFMA16_1K
    return __builtin_amdgcn_mfma_f32_16x16x16bf16_1k(a, b, c, 0, 0, 0);
#else
    f32x4 d;
    asm volatile("v_mfma_f32_16x16x16_bf16 %0, %1, %2, %3"
                 : "=&v"(d) : "v"(a), "v"(b), "v"(c));
    return d;
#endif
}

// ---------------- K1: per-token argmax over 64 sim categories ----------------
__global__ __launch_bounds__(256) void argmax_kernel(const float* __restrict__ sim,
                                                     int* __restrict__ keys) {
    int lane  = threadIdx.x & 63;
    int token = blockIdx.x * 4 + (threadIdx.x >> 6);
    float v = sim[(size_t)token * 64 + lane];
    int idx = lane;
    #pragma unroll
    for (int m = 1; m < 64; m <<= 1) {
        float ov = __shfl_xor(v, m);
        int   oi = __shfl_xor(idx, m);
        if (ov > v || (ov == v && oi < idx)) { v = ov; idx = oi; }
    }
    if (lane == 0) keys[token] = idx;
}

// ---------------- K2: per-tile histogram (tile = 256 tokens) ----------------
__global__ __launch_bounds__(256) void hist_kernel(const int* __restrict__ keys,
                                                   int* __restrict__ counts) {
    __shared__ int hcnt[64];
    int tid  = threadIdx.x;
    int tile = blockIdx.x & (NTILES_ - 1);
    int bz   = blockIdx.x >> 8;
    if (tid < 64) hcnt[tid] = 0;
    __syncthreads();
    int k = keys[bz * N_ + tile * 256 + tid];
    atomicAdd(&hcnt[k], 1);
    __syncthreads();
    if (tid < 64) counts[(bz * NTILES_ + tile) * 64 + tid] = hcnt[tid];
}

// ---------------- K3: two-level scan, 256 threads (64 keys x 4 quarters) -----
__global__ __launch_bounds__(256) void scan_kernel(int* __restrict__ counts) {
    __shared__ int qsum[4][64];
    __shared__ int kbase[64];
    int bz = blockIdx.x;
    int k  = threadIdx.x & 63;
    int qt = threadIdx.x >> 6;
    int base_idx = (bz * NTILES_) * 64 + k;

    int sum = 0;
    #pragma unroll 8
    for (int t = qt * 64; t < qt * 64 + 64; ++t) sum += counts[base_idx + t * 64];
    qsum[qt][k] = sum;
    __syncthreads();

    if (qt == 0) {
        int tot = qsum[0][k] + qsum[1][k] + qsum[2][k] + qsum[3][k];
        int incl = tot;
        #pragma unroll
        for (int off = 1; off < 64; off <<= 1) {
            int v = __shfl_up(incl, off);
            if (k >= off) incl += v;
        }
        kbase[k] = incl - tot;
    }
    __syncthreads();

    int run = kbase[k];
    for (int q2 = 0; q2 < qt; ++q2) run += qsum[q2][k];
    #pragma unroll 8
    for (int t = qt * 64; t < qt * 64 + 64; ++t) {
        int idx = base_idx + t * 64;
        int c = counts[idx];
        counts[idx] = run;
        run += c;
    }
}

// ---------------- K4: stable in-tile rank via match-any ballot ---------------
__global__ __launch_bounds__(256) void rank_kernel(const int* __restrict__ keys,
                                                   const int* __restrict__ counts,
                                                   int* __restrict__ sidx) {
    __shared__ int whist[4 * 64];
    int tid  = threadIdx.x;
    int tile = blockIdx.x & (NTILES_ - 1);
    int bz   = blockIdx.x >> 8;
    whist[tid] = 0;
    __syncthreads();

    int tok = tile * 256 + tid;
    int key = keys[bz * N_ + tok];
    int w = tid >> 6, lane = tid & 63;

    unsigned long long mask = ~0ull;
    #pragma unroll
    for (int b = 0; b < 6; ++b) {
        unsigned long long bb = __ballot((key >> b) & 1);
        mask &= ((key >> b) & 1) ? bb : ~bb;
    }
    unsigned long long lt = (lane == 0) ? 0ull : (~0ull >> (64 - lane));
    int rank = __popcll(mask & lt);
    if (rank == 0) whist[w * 64 + key] = __popcll(mask);
    __syncthreads();

    int base = counts[(bz * NTILES_ + tile) * 64 + key];
    for (int w2 = 0; w2 < w; ++w2) base += whist[w2 * 64 + key];
    int pos = base + rank;
    sidx[bz * N_ + pos] = tok;
}

// ---------------- K5: fused 4-head group attention (DYNAMIC LDS) -------------
// One block = one (b, group); 512 threads (8 waves = 4 heads x 2 q-halves).
// Staging reads CONTIGUOUS per-row granules: Q' 768B, K+V 1536B (amortizes
// DRAM page activations vs 192B per-head gathers). Q' ([Qh|Ql], pre-scaled)
// staged to LDS, pulled to per-lane b-frags, region overwritten by K'
// ([Kh|Kl]); V^T staged alongside. Compute core verbatim R5 (passed on HW).
// LDS = 157696 B > 64 KiB default limit -> MUST be dynamic shared memory with
// hipFuncSetAttribute(MaxDynamicSharedMemorySize). Static >64K launches fail
// SILENTLY (R6-R8 NaNs: kernel never ran, oattn stayed poisoned).
#define KQ_STRIDE 104
#define VT_STRIDE 132
#define KQ_HEAD   (128 * KQ_STRIDE)              // u16 per head
#define KQ_BYTES  (4 * KQ_HEAD * 2)              // 106496
#define VT_HEAD   (48 * VT_STRIDE)
#define VT_BYTES  (4 * VT_HEAD * 2)              // 50688
#define SM_SIZE   (KQ_BYTES + VT_BYTES + 512)    // 157696 <= 160K, 1 block/CU

__global__ __launch_bounds__(512, 2) void attn_kernel(const float* __restrict__ qkv,
                                                      const float* __restrict__ lscale,
                                                      const int* __restrict__ sort_idx,
                                                      unsigned short* __restrict__ oattn) {
    extern __shared__ __align__(16) char smem[];
    unsigned short* kq = (unsigned short*)smem;               // Q' then K' [4][128][104]
    unsigned short* vt = (unsigned short*)(smem + KQ_BYTES);  // V^T [4][48][132]
    int* sidx_s = (int*)(smem + KQ_BYTES + VT_BYTES);

    int g  = blockIdx.x & (NG_ - 1);
    int bz = blockIdx.x >> 9;
    int tid = threadIdx.x;
    if (tid < 128) sidx_s[tid] = sort_idx[bz * N_ + g * GS_ + tid];
    __syncthreads();

    float scale = __expf(fminf(lscale[0], 4.60517019f));

    // ---- Phase 1: stage Q' (scaled, hi/lo split). Row-contiguous 768B reads.
    #pragma unroll 6
    for (int it = 0; it < 12; ++it) {
        int f = it * 512 + tid;
        int row = f / 48, p = f - row * 48;
        int h = p / 12, dk = 4 * (p - h * 12);
        float4 q4 = *(const float4*)(qkv + (size_t)(bz * N_ + sidx_s[row]) * 576 + p * 4);
        q4.x *= scale; q4.y *= scale; q4.z *= scale; q4.w *= scale;
        unsigned h01 = cvt_pk(q4.x, q4.y), h23 = cvt_pk(q4.z, q4.w);
        unsigned l01 = cvt_pk(q4.x - lo16f(h01), q4.y - hi16f(h01));
        unsigned l23 = cvt_pk(q4.z - lo16f(h23), q4.w - hi16f(h23));
        unsigned short* dst = kq + h * KQ_HEAD + row * KQ_STRIDE + dk;
        *(uint2*)dst        = make_uint2(h01, h23);
        *(uint2*)(dst + 48) = make_uint2(l01, l23);
    }
    __syncthreads();

    // ---- Phase 2: pull Q b-frags to registers (per wave: 4 q-tiles x 3 frags)
    int lane = tid & 63, wid = tid >> 6;
    int lr = lane & 15, lg = lane >> 4;
    int hh = wid >> 1, half = wid & 1;
    const unsigned short* qbase = kq + hh * KQ_HEAD;
    short8 qf[4][3];
    int qo1 = (lg < 2) ? (32 + lg * 8) : (48 + (lg - 2) * 8);
    #pragma unroll
    for (int j = 0; j < 4; ++j) {
        const unsigned short* qr = qbase + ((half * 4 + j) * 16 + lr) * KQ_STRIDE;
        qf[j][0] = *(const short8*)(qr + lg * 8);
        qf[j][1] = *(const short8*)(qr + qo1);
        qf[j][2] = *(const short8*)(qr + 64 + lg * 8);
    }
    __syncthreads();

    // ---- Phase 3: stage K' (hi/lo) + V^T. Row-contiguous 1536B reads.
    #pragma unroll 8
    for (int it = 0; it < 24; ++it) {
        int f = it * 512 + tid;
        int row = f / 96, p = f - row * 96;
        float4 v4 = *(const float4*)(qkv + (size_t)(bz * N_ + sidx_s[row]) * 576 + 192 + p * 4);
        if (p < 48) {
            int h = p / 12, dk = 4 * (p - h * 12);
            unsigned h01 = cvt_pk(v4.x, v4.y), h23 = cvt_pk(v4.z, v4.w);
            unsigned l01 = cvt_pk(v4.x - lo16f(h01), v4.y - hi16f(h01));
            unsigned l23 = cvt_pk(v4.z - lo16f(h23), v4.w - hi16f(h23));
            unsigned short* dst = kq + h * KQ_HEAD + row * KQ_STRIDE + dk;
            *(uint2*)dst        = make_uint2(h01, h23);
            *(uint2*)(dst + 48) = make_uint2(l01, l23);
        } else {
            int p2 = p - 48;
            int h = p2 / 12, d0 = 4 * (p2 - h * 12);
            unsigned short* vd = vt + h * VT_HEAD + row;
            vd[(d0 + 0) * VT_STRIDE] = f2bf(v4.x);
            vd[(d0 + 1) * VT_STRIDE] = f2bf(v4.y);
            vd[(d0 + 2) * VT_STRIDE] = f2bf(v4.z);
            vd[(d0 + 3) * VT_STRIDE] = f2bf(v4.w);
        }
    }
    __syncthreads();

    // ---- Phase 4: compute (verbatim R5 core; per-wave, no further barriers) -
    const int boffs[5] = { lg * 8, (32 + lg * 8) % 48, 16 + lg * 8,
                           48 + lg * 8, (lg < 2) ? 80 + lg * 8 : 48 };
    const unsigned short* kb = kq + hh * KQ_HEAD;
    const unsigned short* vb = vt + hh * VT_HEAD;

    #pragma unroll
    for (int pass = 0; pass < 2; ++pass) {
        int j0 = pass * 2, j1 = j0 + 1;
        int qt0 = half * 4 + j0, qt1 = qt0 + 1;

        f32x4 acc0[8], acc1[8];
        #pragma unroll
        for (int kt = 0; kt < 8; ++kt) { acc0[kt] = (f32x4)0.f; acc1[kt] = (f32x4)0.f; }

        #pragma unroll
        for (int s = 0; s < 5; ++s) {
            short8 b0, b1;
            if (s < 3)       { b0 = qf[j0][s]; b1 = qf[j1][s]; }
            else if (s == 3) { b0 = qf[j0][0]; b1 = qf[j1][0]; }
            else             { b0 = (lg < 2) ? qf[j0][1] : (short8)0;
                               b1 = (lg < 2) ? qf[j1][1] : (short8)0; }
            #pragma unroll
            for (int kt = 0; kt < 8; ++kt) {
                short8 a = *(const short8*)(kb + (size_t)(kt * 16 + lr) * KQ_STRIDE + boffs[s]);
                acc0[kt] = __builtin_amdgcn_mfma_f32_16x16x32_bf16(a, b0, acc0[kt], 0, 0, 0);
                acc1[kt] = __builtin_amdgcn_mfma_f32_16x16x32_bf16(a, b1, acc1[kt], 0, 0, 0);
            }
        }

        // softmax: lane owns q-row lr (each qt); k = kt*16 + lg*4 + r
        short4v pf0[8], pf1[8];
        {
            float m0v = -1e30f, m1v = -1e30f;
            #pragma unroll
            for (int kt = 0; kt < 8; ++kt)
                #pragma unroll
                for (int r = 0; r < 4; ++r) {
                    m0v = fmaxf(m0v, acc0[kt][r]);
                    m1v = fmaxf(m1v, acc1[kt][r]);
                }
            m0v = fmaxf(m0v, __shfl_xor(m0v, 16)); m0v = fmaxf(m0v, __shfl_xor(m0v, 32));
            m1v = fmaxf(m1v, __shfl_xor(m1v, 16)); m1v = fmaxf(m1v, __shfl_xor(m1v, 32));
            float s0v = 0.f, s1v = 0.f;
            #pragma unroll
            for (int kt = 0; kt < 8; ++kt)
                #pragma unroll
                for (int r = 0; r < 4; ++r) {
                    float e0 = __expf(acc0[kt][r] - m0v);
                    float e1 = __expf(acc1[kt][r] - m1v);
                    acc0[kt][r] = e0; acc1[kt][r] = e1;
                    s0v += e0; s1v += e1;
                }
            s0v += __shfl_xor(s0v, 16); s0v += __shfl_xor(s0v, 32);
            s1v += __shfl_xor(s1v, 16); s1v += __shfl_xor(s1v, 32);
            float inv0 = 1.f / s0v, inv1 = 1.f / s1v;
            #pragma unroll
            for (int kt = 0; kt < 8; ++kt) {
                union { short4v v; unsigned u[2]; } u0, u1;
                u0.u[0] = cvt_pk(acc0[kt][0] * inv0, acc0[kt][1] * inv0);
                u0.u[1] = cvt_pk(acc0[kt][2] * inv0, acc0[kt][3] * inv0);
                u1.u[0] = cvt_pk(acc1[kt][0] * inv1, acc1[kt][1] * inv1);
                u1.u[1] = cvt_pk(acc1[kt][2] * inv1, acc1[kt][3] * inv1);
                pf0[kt] = u0.v; pf1[kt] = u1.v;
            }
        }

        // PV: 16x16x16, A = P regs, B = V^T LDS
        f32x4 o0[3], o1[3];
        #pragma unroll
        for (int dt = 0; dt < 3; ++dt) { o0[dt] = (f32x4)0.f; o1[dt] = (f32x4)0.f; }
        #pragma unroll
        for (int kt = 0; kt < 8; ++kt) {
            #pragma unroll
            for (int dt = 0; dt < 3; ++dt) {
                short4v vf = *(const short4v*)(vb + (size_t)(dt * 16 + lr) * VT_STRIDE + kt * 16 + lg * 4);
                o0[dt] = mfma16(pf0[kt], vf, o0[dt]);
                o1[dt] = mfma16(pf1[kt], vf, o1[dt]);
            }
        }

        // store: O rows = lg*4+r, cols = dt*16+lr
        #pragma unroll
        for (int dt = 0; dt < 3; ++dt)
            #pragma unroll
            for (int r = 0; r < 4; ++r) {
                int row0 = qt0 * 16 + lg * 4 + r;
                int row1 = qt1 * 16 + lg * 4 + r;
                oattn[(size_t)(bz * N_ + g * GS_ + row0) * C_ + hh * HD_ + dt * 16 + lr] = f2bf(o0[dt][r]);
                oattn[(size_t)(bz * N_ + g * GS_ + row1) * C_ + hh * HD_ + dt * 16 + lr] = f2bf(o1[dt][r]);
            }
    }
}

// ---------------- K6a: convert W (192x192 fp32) to bf16 ----------------------
__global__ __launch_bounds__(256) void wconv_kernel(const float* __restrict__ W,
                                                    unsigned short* __restrict__ wbf) {
    int i = blockIdx.x * 256 + threadIdx.x;
    float4 f = ((const float4*)W)[i];
    uint2 p;
    p.x = (unsigned)f2bf(f.x) | ((unsigned)f2bf(f.y) << 16);
    p.y = (unsigned)f2bf(f.z) | ((unsigned)f2bf(f.w) << 16);
    ((uint2*)wbf)[i] = p;
}

// ---------------- K6b: x @ W^T + b via MFMA; contiguous reads, scatter stores -
__global__ __launch_bounds__(256) void proj2_kernel(const unsigned short* __restrict__ oattn,
                                                    const int* __restrict__ sidx,
                                                    const unsigned short* __restrict__ wbf,
                                                    const float* __restrict__ bias,
                                                    float* __restrict__ out) {
    __shared__ int mout[128];
    int tid = threadIdx.x;
    int s0  = blockIdx.x * 128;

    if (tid < 128) {
        int s = s0 + tid;
        int bz = s >> 16;
        mout[tid] = bz * N_ + sidx[s];
    }
    __syncthreads();

    int lane = tid & 63, wid = tid >> 6;
    int lr = lane & 15, lg = lane >> 4;
    int mt0 = wid * 2, mt1 = wid * 2 + 1;

    const unsigned short* xr0 = oattn + (size_t)(s0 + mt0 * 16 + lr) * C_ + lg * 8;
    const unsigned short* xr1 = oattn + (size_t)(s0 + mt1 * 16 + lr) * C_ + lg * 8;
    const unsigned short* wr  = wbf + (size_t)lr * C_ + lg * 8;

    f32x4 acc[2][12];
    #pragma unroll
    for (int mt = 0; mt < 2; ++mt)
        #pragma unroll
        for (int jt = 0; jt < 12; ++jt) acc[mt][jt] = (f32x4)0.f;

    #pragma unroll
    for (int ks = 0; ks < 6; ++ks) {
        short8 a0 = *(const short8*)(xr0 + ks * 32);
        short8 a1 = *(const short8*)(xr1 + ks * 32);
        #pragma unroll
        for (int jt = 0; jt < 12; ++jt) {
            short8 b = *(const short8*)(wr + (size_t)jt * 16 * C_ + ks * 32);
            acc[0][jt] = __builtin_amdgcn_mfma_f32_16x16x32_bf16(a0, b, acc[0][jt], 0, 0, 0);
            acc[1][jt] = __builtin_amdgcn_mfma_f32_16x16x32_bf16(a1, b, acc[1][jt], 0, 0, 0);
        }
    }

    #pragma unroll
    for (int jt = 0; jt < 12; ++jt) {
        int j = jt * 16 + lr;
        float bj = bias[j];
        #pragma unroll
        for (int r = 0; r < 4; ++r) {
            int row0 = mout[mt0 * 16 + lg * 4 + r];
            int row1 = mout[mt1 * 16 + lg * 4 + r];
            out[(size_t)row0 * C_ + j] = acc[0][jt][r] + bj;
            out[(size_t)row1 * C_ + j] = acc[1][jt][r] + bj;
        }
    }
}

extern "C" void kernel_launch(void* const* d_in, const int* in_sizes, int n_in,
                              void* d_out, int out_size, void* d_ws, size_t ws_size,
                              hipStream_t stream) {
    const float* qkv    = (const float*)d_in[0];
    const float* sim    = (const float*)d_in[1];
    const float* proj_w = (const float*)d_in[2];
    const float* proj_b = (const float*)d_in[3];
    const float* lscale = (const float*)d_in[4];
    float* out = (float*)d_out;

    char* ws = (char*)d_ws;
    int* keys   = (int*)(ws);
    int* sidx   = (int*)(ws + 1048576);
    int* counts = (int*)(ws + 1572864);
    unsigned short* oattn = (unsigned short*)(ws + 1703936);            // 50331648 B
    unsigned short* wbf   = (unsigned short*)(ws + 1703936 + 50331648); // 73728 B

    // Raise the dynamic-LDS cap to 157696 B (>64K default). Host-side config
    // call, not a stream op: graph-capture-safe; idempotent across calls.
    static_assert(SM_SIZE <= 163840, "LDS over 160K");
    (void)hipFuncSetAttribute((const void*)attn_kernel,
                              hipFuncAttributeMaxDynamicSharedMemorySize, SM_SIZE);

    argmax_kernel<<<32768, 256, 0, stream>>>(sim, keys);
    hist_kernel<<<B_ * NTILES_, 256, 0, stream>>>(keys, counts);
    scan_kernel<<<B_, 256, 0, stream>>>(counts);
    rank_kernel<<<B_ * NTILES_, 256, 0, stream>>>(keys, counts, sidx);
    wconv_kernel<<<36, 256, 0, stream>>>(proj_w, wbf);
    attn_kernel<<<B_ * NG_, 512, SM_SIZE, stream>>>(qkv, lscale, sidx, oattn);
    proj2_kernel<<<(B_ * N_) / 128, 256, 0, stream>>>(oattn, sidx, wbf, proj_b, out);
}

// Round 12
// 216.787 us; speedup vs baseline: 1.1858x; 1.1858x over previous
//
#include <hip/hip_runtime.h>

#define B_  2
#define N_  65536
#define C_  192
#define NH_ 4
#define HD_ 48
#define GS_ 128
#define NG_ 512
#define NTILES_ 256   // per batch, tile = 256 tokens

typedef __attribute__((ext_vector_type(8))) short short8;
typedef __attribute__((ext_vector_type(4))) float f32x4;

__device__ __forceinline__ unsigned short f2bf(float f) {
    unsigned u = __float_as_uint(f);
    unsigned r = (u + 0x7FFFu + ((u >> 16) & 1u)) >> 16;
    return (unsigned short)r;
}
__device__ __forceinline__ float bf2f(unsigned short s) {
    return __uint_as_float(((unsigned)s) << 16);
}
// packed RNE f32x2 -> bf16x2 (low short = a, high short = b)
__device__ __forceinline__ unsigned cvt_pk(float a, float b) {
    unsigned r;
    asm("v_cvt_pk_bf16_f32 %0, %1, %2" : "=v"(r) : "v"(a), "v"(b));
    return r;
}

// ---------------- K1: per-token argmax over 64 sim categories ----------------
__global__ __launch_bounds__(256) void argmax_kernel(const float* __restrict__ sim,
                                                     int* __restrict__ keys) {
    int lane  = threadIdx.x & 63;
    int token = blockIdx.x * 4 + (threadIdx.x >> 6);
    float v = sim[(size_t)token * 64 + lane];
    int idx = lane;
    #pragma unroll
    for (int m = 1; m < 64; m <<= 1) {
        float ov = __shfl_xor(v, m);
        int   oi = __shfl_xor(idx, m);
        if (ov > v || (ov == v && oi < idx)) { v = ov; idx = oi; }
    }
    if (lane == 0) keys[token] = idx;
}

// ---------------- K2: per-tile histogram (tile = 256 tokens) ----------------
__global__ __launch_bounds__(256) void hist_kernel(const int* __restrict__ keys,
                                                   int* __restrict__ counts) {
    __shared__ int hcnt[64];
    int tid  = threadIdx.x;
    int tile = blockIdx.x & (NTILES_ - 1);
    int bz   = blockIdx.x >> 8;
    if (tid < 64) hcnt[tid] = 0;
    __syncthreads();
    int k = keys[bz * N_ + tile * 256 + tid];
    atomicAdd(&hcnt[k], 1);
    __syncthreads();
    if (tid < 64) counts[(bz * NTILES_ + tile) * 64 + tid] = hcnt[tid];
}

// ---------------- K3: two-level scan, 256 threads (64 keys x 4 quarters) -----
__global__ __launch_bounds__(256) void scan_kernel(int* __restrict__ counts) {
    __shared__ int qsum[4][64];
    __shared__ int kbase[64];
    int bz = blockIdx.x;
    int k  = threadIdx.x & 63;
    int qt = threadIdx.x >> 6;
    int base_idx = (bz * NTILES_) * 64 + k;

    int sum = 0;
    #pragma unroll 8
    for (int t = qt * 64; t < qt * 64 + 64; ++t) sum += counts[base_idx + t * 64];
    qsum[qt][k] = sum;
    __syncthreads();

    if (qt == 0) {
        int tot = qsum[0][k] + qsum[1][k] + qsum[2][k] + qsum[3][k];
        int incl = tot;
        #pragma unroll
        for (int off = 1; off < 64; off <<= 1) {
            int v = __shfl_up(incl, off);
            if (k >= off) incl += v;
        }
        kbase[k] = incl - tot;
    }
    __syncthreads();

    int run = kbase[k];
    for (int q2 = 0; q2 < qt; ++q2) run += qsum[q2][k];
    #pragma unroll 8
    for (int t = qt * 64; t < qt * 64 + 64; ++t) {
        int idx = base_idx + t * 64;
        int c = counts[idx];
        counts[idx] = run;
        run += c;
    }
}

// ---------------- K4: stable in-tile rank via match-any ballot ---------------
__global__ __launch_bounds__(256) void rank_kernel(const int* __restrict__ keys,
                                                   const int* __restrict__ counts,
                                                   int* __restrict__ sidx,
                                                   int* __restrict__ dest) {
    __shared__ int whist[4 * 64];
    int tid  = threadIdx.x;
    int tile = blockIdx.x & (NTILES_ - 1);
    int bz   = blockIdx.x >> 8;
    whist[tid] = 0;
    __syncthreads();

    int tok = tile * 256 + tid;
    int key = keys[bz * N_ + tok];
    int w = tid >> 6, lane = tid & 63;

    unsigned long long mask = ~0ull;
    #pragma unroll
    for (int b = 0; b < 6; ++b) {
        unsigned long long bb = __ballot((key >> b) & 1);
        mask &= ((key >> b) & 1) ? bb : ~bb;
    }
    unsigned long long lt = (lane == 0) ? 0ull : (~0ull >> (64 - lane));
    int rank = __popcll(mask & lt);
    if (rank == 0) whist[w * 64 + key] = __popcll(mask);
    __syncthreads();

    int base = counts[(bz * NTILES_ + tile) * 64 + key];
    for (int w2 = 0; w2 < w; ++w2) base += whist[w2 * 64 + key];
    int pos = base + rank;
    sidx[bz * N_ + pos] = tok;
    dest[bz * N_ + tok] = pos;
}

// ---------------- K5: MFMA grouped attention (latency-optimized) -------------
// K' = [Kh|Kl] (stride 104). QK^T = pass1 [Qh|Ql]x[Kh|Kh] (3 steps) +
// pass2 Qh x Kl (2 steps, zero-padded tail). Q hoisted to registers. P[128][136]
// overlays K' after one barrier; P rows are wave-private -> no second barrier.
#define KP_STRIDE 104
#define P_STRIDE  136
#define VT_STRIDE 136
#define SM_VT   34816              // max(128*104*2, 128*136*2)
#define SM_SIDX (SM_VT + 48*VT_STRIDE*2)
#define SM_SIZE (SM_SIDX + 512)

__global__ __launch_bounds__(256, 3) void attn_kernel(const float* __restrict__ qkv,
                                                      const float* __restrict__ lscale,
                                                      const int* __restrict__ sort_idx,
                                                      unsigned short* __restrict__ oattn) {
    __shared__ __align__(16) char smem[SM_SIZE];
    unsigned short* kp = (unsigned short*)smem;          // K' [128][104]; later P [128][136]
    unsigned short* vt = (unsigned short*)(smem + SM_VT);// V^T [48][136]
    int* sidx_s = (int*)(smem + SM_SIDX);

    int x  = blockIdx.x;
    int h  = x & 3;
    int g  = (x >> 2) & (NG_ - 1);
    int bz = x >> 11;
    int tid = threadIdx.x;

    if (tid < 128) sidx_s[tid] = sort_idx[bz * N_ + g * GS_ + tid];
    __syncthreads();

    int lane = tid & 63, wid = tid >> 6;
    int lr = lane & 15, lg = lane >> 4;
    int qt0 = wid * 2, qt1 = qt0 + 1;
    float scale = __expf(fminf(lscale[0], 4.60517019f));

    // ---- hoisted Q gather loads: 3 ranges x 2 float4 x 2 rows ----
    int r0s = lg * 8;
    int r1s = 16 + lg * 8;
    int r2s = (lg < 2) ? 32 + lg * 8 : (lg - 2) * 8;
    const float* q0p = qkv + (size_t)(bz * N_ + sidx_s[qt0 * 16 + lr]) * 576 + h * 48;
    const float* q1p = qkv + (size_t)(bz * N_ + sidx_s[qt1 * 16 + lr]) * 576 + h * 48;
    float4 qA0 = *(const float4*)(q0p + r0s), qA1 = *(const float4*)(q0p + r0s + 4);
    float4 qB0 = *(const float4*)(q0p + r1s), qB1 = *(const float4*)(q0p + r1s + 4);
    float4 qC0 = *(const float4*)(q0p + r2s), qC1 = *(const float4*)(q0p + r2s + 4);
    float4 pA0 = *(const float4*)(q1p + r0s), pA1 = *(const float4*)(q1p + r0s + 4);
    float4 pB0 = *(const float4*)(q1p + r1s), pB1 = *(const float4*)(q1p + r1s + 4);
    float4 pC0 = *(const float4*)(q1p + r2s), pC1 = *(const float4*)(q1p + r2s + 4);

    // ---- stage K (flat coalesced): 1536 float4 over 256 threads ----
    #pragma unroll
    for (int it = 0; it < 6; ++it) {
        int f = it * 256 + tid;
        int row = f / 12, piece = f - row * 12;
        float4 kf = *(const float4*)(qkv + (size_t)(bz * N_ + sidx_s[row]) * 576 + 192 + h * 48 + piece * 4);
        unsigned h01 = cvt_pk(kf.x, kf.y), h23 = cvt_pk(kf.z, kf.w);
        float hx = __uint_as_float(h01 << 16), hy = __uint_as_float(h01 & 0xFFFF0000u);
        float hz = __uint_as_float(h23 << 16), hw = __uint_as_float(h23 & 0xFFFF0000u);
        unsigned l01 = cvt_pk(kf.x - hx, kf.y - hy), l23 = cvt_pk(kf.z - hz, kf.w - hw);
        *(uint2*)(kp + row * KP_STRIDE + piece * 4)      = make_uint2(h01, h23);
        *(uint2*)(kp + row * KP_STRIDE + 48 + piece * 4) = make_uint2(l01, l23);
    }
    // ---- stage V^T (flat coalesced) ----
    #pragma unroll
    for (int it = 0; it < 6; ++it) {
        int f = it * 256 + tid;
        int row = f / 12, piece = f - row * 12;
        float4 vf = *(const float4*)(qkv + (size_t)(bz * N_ + sidx_s[row]) * 576 + 384 + h * 48 + piece * 4);
        int d = piece * 4;
        vt[(d + 0) * VT_STRIDE + row] = f2bf(vf.x);
        vt[(d + 1) * VT_STRIDE + row] = f2bf(vf.y);
        vt[(d + 2) * VT_STRIDE + row] = f2bf(vf.z);
        vt[(d + 3) * VT_STRIDE + row] = f2bf(vf.w);
    }

    // ---- convert Q (pre-scaled) to a-frags: af[s][w] dwords ----
    unsigned af0[5][4], af1[5][4];
    {
        float a0[8] = {qA0.x,qA0.y,qA0.z,qA0.w,qA1.x,qA1.y,qA1.z,qA1.w};
        float b0[8] = {qB0.x,qB0.y,qB0.z,qB0.w,qB1.x,qB1.y,qB1.z,qB1.w};
        float c0[8] = {qC0.x,qC0.y,qC0.z,qC0.w,qC1.x,qC1.y,qC1.z,qC1.w};
        float a1[8] = {pA0.x,pA0.y,pA0.z,pA0.w,pA1.x,pA1.y,pA1.z,pA1.w};
        float b1[8] = {pB0.x,pB0.y,pB0.z,pB0.w,pB1.x,pB1.y,pB1.z,pB1.w};
        float c1[8] = {pC0.x,pC0.y,pC0.z,pC0.w,pC1.x,pC1.y,pC1.z,pC1.w};
        #pragma unroll
        for (int j = 0; j < 8; ++j) {
            a0[j] *= scale; b0[j] *= scale; c0[j] *= scale;
            a1[j] *= scale; b1[j] *= scale; c1[j] *= scale;
        }
        #pragma unroll
        for (int w = 0; w < 4; ++w) {
            // F0 = hi(r0) : steps 0 and 3
            af0[0][w] = cvt_pk(a0[2*w], a0[2*w+1]);
            af1[0][w] = cvt_pk(a1[2*w], a1[2*w+1]);
            af0[3][w] = af0[0][w];
            af1[3][w] = af1[0][w];
            // F2 = lo(r1) : step 2
            {
                unsigned t0 = cvt_pk(b0[2*w], b0[2*w+1]);
                float hx = __uint_as_float(t0 << 16), hy = __uint_as_float(t0 & 0xFFFF0000u);
                af0[2][w] = cvt_pk(b0[2*w] - hx, b0[2*w+1] - hy);
                unsigned t1 = cvt_pk(b1[2*w], b1[2*w+1]);
                float ix = __uint_as_float(t1 << 16), iy = __uint_as_float(t1 & 0xFFFF0000u);
                af1[2][w] = cvt_pk(b1[2*w] - ix, b1[2*w+1] - iy);
            }
            // F1 = lg<2 ? hi(r2) : lo(r2) : step 1; step 4 = lg<2 ? F1 : 0
            if (lg < 2) {
                af0[1][w] = cvt_pk(c0[2*w], c0[2*w+1]);
                af1[1][w] = cvt_pk(c1[2*w], c1[2*w+1]);
                af0[4][w] = af0[1][w];
                af1[4][w] = af1[1][w];
            } else {
                unsigned t0 = cvt_pk(c0[2*w], c0[2*w+1]);
                float hx = __uint_as_float(t0 << 16), hy = __uint_as_float(t0 & 0xFFFF0000u);
                af0[1][w] = cvt_pk(c0[2*w] - hx, c0[2*w+1] - hy);
                unsigned t1 = cvt_pk(c1[2*w], c1[2*w+1]);
                float ix = __uint_as_float(t1 << 16), iy = __uint_as_float(t1 & 0xFFFF0000u);
                af1[1][w] = cvt_pk(c1[2*w] - ix, c1[2*w+1] - iy);
                af0[4][w] = 0; af1[4][w] = 0;
            }
        }
    }
    __syncthreads();

    // ---- QK^T: 5 steps, b-frag offsets into [Kh(0..47)|Kl(48..95)] ----
    const int boffs[5] = { lg * 8, (32 + lg * 8) % 48, 16 + lg * 8,
                           48 + lg * 8, (lg < 2) ? 80 + lg * 8 : 48 };
    f32x4 acc0[8], acc1[8];
    #pragma unroll
    for (int kt = 0; kt < 8; ++kt) { acc0[kt] = (f32x4)0.f; acc1[kt] = (f32x4)0.f; }

    #pragma unroll
    for (int s = 0; s < 5; ++s) {
        union { short8 v; unsigned u[4]; } ua, ub;
        #pragma unroll
        for (int w = 0; w < 4; ++w) { ua.u[w] = af0[s][w]; ub.u[w] = af1[s][w]; }
        short8 a0 = ua.v, a1 = ub.v;
        #pragma unroll
        for (int kt = 0; kt < 8; ++kt) {
            short8 b = *(const short8*)(kp + (size_t)(kt * 16 + lr) * KP_STRIDE + boffs[s]);
            acc0[kt] = __builtin_amdgcn_mfma_f32_16x16x32_bf16(a0, b, acc0[kt], 0, 0, 0);
            acc1[kt] = __builtin_amdgcn_mfma_f32_16x16x32_bf16(a1, b, acc1[kt], 0, 0, 0);
        }
    }

    // ---- softmax (rows = lg*4+r, cols = kt*16+lr); scale already folded ----
    float inv0[4], inv1[4];
    {
        float mx0[4], mx1[4];
        #pragma unroll
        for (int r = 0; r < 4; ++r) { mx0[r] = -1e30f; mx1[r] = -1e30f; }
        #pragma unroll
        for (int kt = 0; kt < 8; ++kt)
            #pragma unroll
            for (int r = 0; r < 4; ++r) {
                mx0[r] = fmaxf(mx0[r], acc0[kt][r]);
                mx1[r] = fmaxf(mx1[r], acc1[kt][r]);
            }
        #pragma unroll
        for (int m = 1; m < 16; m <<= 1)
            #pragma unroll
            for (int r = 0; r < 4; ++r) {
                mx0[r] = fmaxf(mx0[r], __shfl_xor(mx0[r], m));
                mx1[r] = fmaxf(mx1[r], __shfl_xor(mx1[r], m));
            }
        float sm0[4] = {0.f,0.f,0.f,0.f}, sm1[4] = {0.f,0.f,0.f,0.f};
        #pragma unroll
        for (int kt = 0; kt < 8; ++kt)
            #pragma unroll
            for (int r = 0; r < 4; ++r) {
                float e0 = __expf(acc0[kt][r] - mx0[r]);
                float e1 = __expf(acc1[kt][r] - mx1[r]);
                acc0[kt][r] = e0; acc1[kt][r] = e1;
                sm0[r] += e0; sm1[r] += e1;
            }
        #pragma unroll
        for (int m = 1; m < 16; m <<= 1)
            #pragma unroll
            for (int r = 0; r < 4; ++r) {
                sm0[r] += __shfl_xor(sm0[r], m);
                sm1[r] += __shfl_xor(sm1[r], m);
            }
        #pragma unroll
        for (int r = 0; r < 4; ++r) { inv0[r] = 1.f / sm0[r]; inv1[r] = 1.f / sm1[r]; }
    }

    __syncthreads();   // all waves done reading K' before P overwrites region

    // ---- write P (bf16, unnormalized) into own wave's rows; no barrier ----
    #pragma unroll
    for (int kt = 0; kt < 8; ++kt)
        #pragma unroll
        for (int r = 0; r < 4; ++r) {
            kp[(size_t)(qt0 * 16 + lg * 4 + r) * P_STRIDE + kt * 16 + lr] = (unsigned short)cvt_pk(acc0[kt][r], acc0[kt][r]);
            kp[(size_t)(qt1 * 16 + lg * 4 + r) * P_STRIDE + kt * 16 + lr] = (unsigned short)cvt_pk(acc1[kt][r], acc1[kt][r]);
        }

    // ---- PV (reads own wave's P rows + vt) ----
    f32x4 o0[3], o1[3];
    #pragma unroll
    for (int dt = 0; dt < 3; ++dt) { o0[dt] = (f32x4)0.f; o1[dt] = (f32x4)0.f; }
    #pragma unroll
    for (int ks = 0; ks < 4; ++ks) {
        short8 a0 = *(const short8*)(kp + (size_t)(qt0 * 16 + lr) * P_STRIDE + ks * 32 + lg * 8);
        short8 a1 = *(const short8*)(kp + (size_t)(qt1 * 16 + lr) * P_STRIDE + ks * 32 + lg * 8);
        #pragma unroll
        for (int dt = 0; dt < 3; ++dt) {
            short8 bv = *(const short8*)(vt + (size_t)(dt * 16 + lr) * VT_STRIDE + ks * 32 + lg * 8);
            o0[dt] = __builtin_amdgcn_mfma_f32_16x16x32_bf16(a0, bv, o0[dt], 0, 0, 0);
            o1[dt] = __builtin_amdgcn_mfma_f32_16x16x32_bf16(a1, bv, o1[dt], 0, 0, 0);
        }
    }

    // ---- store (normalize by row sums) ----
    #pragma unroll
    for (int dt = 0; dt < 3; ++dt)
        #pragma unroll
        for (int r = 0; r < 4; ++r) {
            int row0 = qt0 * 16 + lg * 4 + r;
            int row1 = qt1 * 16 + lg * 4 + r;
            oattn[(size_t)(bz * N_ + g * GS_ + row0) * C_ + h * HD_ + dt * 16 + lr] =
                f2bf(o0[dt][r] * inv0[r]);
            oattn[(size_t)(bz * N_ + g * GS_ + row1) * C_ + h * HD_ + dt * 16 + lr] =
                f2bf(o1[dt][r] * inv1[r]);
        }
}

// ---------------- K6a: convert W (192x192 fp32) to bf16 ----------------------
__global__ __launch_bounds__(256) void wconv_kernel(const float* __restrict__ W,
                                                    unsigned short* __restrict__ wbf) {
    int i = blockIdx.x * 256 + threadIdx.x;
    float4 f = ((const float4*)W)[i];
    uint2 p;
    p.x = (unsigned)f2bf(f.x) | ((unsigned)f2bf(f.y) << 16);
    p.y = (unsigned)f2bf(f.z) | ((unsigned)f2bf(f.w) << 16);
    ((uint2*)wbf)[i] = p;
}

// ---------------- K6b: unshuffle + x @ W^T + b via MFMA ----------------------
__global__ __launch_bounds__(256) void proj2_kernel(const unsigned short* __restrict__ oattn,
                                                    const int* __restrict__ dest,
                                                    const unsigned short* __restrict__ wbf,
                                                    const float* __restrict__ bias,
                                                    float* __restrict__ out) {
    __shared__ int mpos[128];
    int tid = threadIdx.x;
    int m0  = blockIdx.x * 128;

    if (tid < 128) {
        int m = m0 + tid;
        int bz = m >> 16;
        mpos[tid] = bz * N_ + dest[m];
    }
    __syncthreads();

    int lane = tid & 63, wid = tid >> 6;
    int lr = lane & 15, lg = lane >> 4;
    int mt0 = wid * 2, mt1 = wid * 2 + 1;

    const unsigned short* xr0 = oattn + (size_t)mpos[mt0 * 16 + lr] * C_ + lg * 8;
    const unsigned short* xr1 = oattn + (size_t)mpos[mt1 * 16 + lr] * C_ + lg * 8;
    const unsigned short* wr  = wbf + (size_t)lr * C_ + lg * 8;

    f32x4 acc[2][12];
    #pragma unroll
    for (int mt = 0; mt < 2; ++mt)
        #pragma unroll
        for (int jt = 0; jt < 12; ++jt) acc[mt][jt] = (f32x4)0.f;

    #pragma unroll
    for (int ks = 0; ks < 6; ++ks) {
        short8 a0 = *(const short8*)(xr0 + ks * 32);
        short8 a1 = *(const short8*)(xr1 + ks * 32);
        #pragma unroll
        for (int jt = 0; jt < 12; ++jt) {
            short8 b = *(const short8*)(wr + (size_t)jt * 16 * C_ + ks * 32);
            acc[0][jt] = __builtin_amdgcn_mfma_f32_16x16x32_bf16(a0, b, acc[0][jt], 0, 0, 0);
            acc[1][jt] = __builtin_amdgcn_mfma_f32_16x16x32_bf16(a1, b, acc[1][jt], 0, 0, 0);
        }
    }

    #pragma unroll
    for (int jt = 0; jt < 12; ++jt) {
        int j = jt * 16 + lr;
        float bj = bias[j];
        #pragma unroll
        for (int r = 0; r < 4; ++r) {
            int row0 = m0 + mt0 * 16 + lg * 4 + r;
            int row1 = m0 + mt1 * 16 + lg * 4 + r;
            out[(size_t)row0 * C_ + j] = acc[0][jt][r] + bj;
            out[(size_t)row1 * C_ + j] = acc[1][jt][r] + bj;
        }
    }
}

extern "C" void kernel_launch(void* const* d_in, const int* in_sizes, int n_in,
                              void* d_out, int out_size, void* d_ws, size_t ws_size,
                              hipStream_t stream) {
    const float* qkv    = (const float*)d_in[0];
    const float* sim    = (const float*)d_in[1];
    const float* proj_w = (const float*)d_in[2];
    const float* proj_b = (const float*)d_in[3];
    const float* lscale = (const float*)d_in[4];
    float* out = (float*)d_out;

    char* ws = (char*)d_ws;
    int* keys   = (int*)(ws);
    int* dest   = (int*)(ws + 524288);
    int* sidx   = (int*)(ws + 1048576);
    int* counts = (int*)(ws + 1572864);
    unsigned short* oattn = (unsigned short*)(ws + 1703936);            // 50331648 B
    unsigned short* wbf   = (unsigned short*)(ws + 1703936 + 50331648); // 73728 B

    argmax_kernel<<<32768, 256, 0, stream>>>(sim, keys);
    hist_kernel<<<B_ * NTILES_, 256, 0, stream>>>(keys, counts);
    scan_kernel<<<B_, 256, 0, stream>>>(counts);
    rank_kernel<<<B_ * NTILES_, 256, 0, stream>>>(keys, counts, sidx, dest);
    wconv_kernel<<<36, 256, 0, stream>>>(proj_w, wbf);
    attn_kernel<<<B_ * NG_ * NH_, 256, 0, stream>>>(qkv, lscale, sidx, oattn);
    proj2_kernel<<<dim3((B_ * N_) / 128), 256, 0, stream>>>(oattn, dest, wbf, proj_b, out);
}